// Round 5
// baseline (305.120 us; speedup 1.0000x reference)
//
#include <hip/hip_runtime.h>

#define M_DIM 4096
#define N_DIM 4096
#define K_DIM 4096

typedef float f32x16 __attribute__((ext_vector_type(16)));
typedef __bf16 bf16x8 __attribute__((ext_vector_type(8)));

// round-to-nearest-even fp32 -> bf16
__device__ __forceinline__ unsigned short f2b(float f) {
    unsigned int u = __float_as_uint(f);
    u += 0x7fffu + ((u >> 16) & 1u);
    return (unsigned short)(u >> 16);
}

// Arithmetic NVFP4 (e2m1) decode — pure VALU, bit-exact vs the codebook.
__device__ __forceinline__ float nvfp4_decode(int n) {
    unsigned m = (unsigned)n & 7u;
    unsigned e = m >> 1, f = m & 1u;
    unsigned bits = (m >= 2u) ? (((126u + e) << 23) | (f << 22))
                              : (m * 0x3f000000u);   // 0 -> 0.0f, 1 -> 0.5f
    bits |= ((unsigned)n & 8u) << 28;                 // sign
    return __uint_as_float(bits);
}

// ---------------------------------------------------------------------------
// Prep: separate high-occupancy streaming kernels (proven ~31us total =
// traffic roofline; fusing into the 1-block/CU gemm regressed to ~115us).
// ---------------------------------------------------------------------------
__global__ __launch_bounds__(256) void xconv_kernel(
        const float* __restrict__ x, unsigned short* __restrict__ xb) {
    size_t i = ((size_t)blockIdx.x * 256 + threadIdx.x) * 8;
    float4 a0 = *(const float4*)(x + i);
    float4 a1 = *(const float4*)(x + i + 4);
    union { unsigned short h[8]; uint4 u; } o;
    o.h[0] = f2b(a0.x); o.h[1] = f2b(a0.y); o.h[2] = f2b(a0.z); o.h[3] = f2b(a0.w);
    o.h[4] = f2b(a1.x); o.h[5] = f2b(a1.y); o.h[6] = f2b(a1.z); o.h[7] = f2b(a1.w);
    *(uint4*)(xb + i) = o.u;
}

__global__ __launch_bounds__(256) void wbuild_kernel(
        const int* __restrict__ idx4, const float* __restrict__ sc4,
        const float* __restrict__ gs4, const float* __restrict__ w8,
        const float* __restrict__ s8, const float* __restrict__ w16,
        const int* __restrict__ iperm, unsigned short* __restrict__ W) {
    const int j = blockIdx.x;
    const int t = threadIdx.x;
    const int g = iperm[j];

#pragma unroll
    for (int h = 0; h < 2; ++h) {
        const int k0 = h * 2048 + t * 8;   // 8 elems / thread / half
        union { unsigned short hh[8]; uint4 u; } o;
        if (g < 2048) {
            const float s = sc4[(size_t)g * (K_DIM / 16) + (k0 >> 4)] * gs4[0];
            const int4* ip = (const int4*)(idx4 + (size_t)g * K_DIM + k0);
            int4 v0 = ip[0], v1 = ip[1];
            o.hh[0] = f2b(nvfp4_decode(v0.x) * s);
            o.hh[1] = f2b(nvfp4_decode(v0.y) * s);
            o.hh[2] = f2b(nvfp4_decode(v0.z) * s);
            o.hh[3] = f2b(nvfp4_decode(v0.w) * s);
            o.hh[4] = f2b(nvfp4_decode(v1.x) * s);
            o.hh[5] = f2b(nvfp4_decode(v1.y) * s);
            o.hh[6] = f2b(nvfp4_decode(v1.z) * s);
            o.hh[7] = f2b(nvfp4_decode(v1.w) * s);
        } else if (g < 3072) {
            const float s = s8[0];
            const float4* wp = (const float4*)(w8 + (size_t)(g - 2048) * K_DIM + k0);
            float4 v0 = wp[0], v1 = wp[1];
            o.hh[0] = f2b(v0.x * s); o.hh[1] = f2b(v0.y * s);
            o.hh[2] = f2b(v0.z * s); o.hh[3] = f2b(v0.w * s);
            o.hh[4] = f2b(v1.x * s); o.hh[5] = f2b(v1.y * s);
            o.hh[6] = f2b(v1.z * s); o.hh[7] = f2b(v1.w * s);
        } else {
            const float4* wp = (const float4*)(w16 + (size_t)(g - 3072) * K_DIM + k0);
            float4 v0 = wp[0], v1 = wp[1];
            o.hh[0] = f2b(v0.x); o.hh[1] = f2b(v0.y);
            o.hh[2] = f2b(v0.z); o.hh[3] = f2b(v0.w);
            o.hh[4] = f2b(v1.x); o.hh[5] = f2b(v1.y);
            o.hh[6] = f2b(v1.z); o.hh[7] = f2b(v1.w);
        }
        *(uint4*)(W + (size_t)j * K_DIM + k0) = o.u;
    }
}

// ---------------------------------------------------------------------------
// GEMM: C[M,N] = Xb[M,K] * Wb[N,K]^T + bias
// R5: switch MFMA shape 16x16x32 -> 32x32x16 (ceiling 2075 -> 2382+ TF,
// instruction count halves at fixed LDS traffic). Keeps R4's pure
// double-buffer skeleton: ONE vmcnt(0) + ONE barrier per K-tile.
//
// 256x256 tile, BK=64, 8 waves (2Mx4N), per-wave output 128x64 =
// 4 fm x 2 fn frags of 32x32, 4 k-steps of 16 -> 32 MFMA/wave/K-tile.
//
// Fragment layout (analogy with the verified 16x16x32 kernel; C/D is the
// m74-verified mapping):
//   A: lane holds A[row = lane&31][k = (lane>>5)*8 + 0..7]  (1 b128/frag)
//   B: lane holds W[col = lane&31][k = (lane>>5)*8 + 0..7]  (same addressing)
//   C/D: col = lane&31, row = (reg&3) + 8*(reg>>2) + 4*(lane>>5)
//
// LDS: per buffer A 32KB + B 32KB; subtile = 32 rows x 128B (4KB), one per
// wave-ownership unit. Swizzle: within each row, 16B chunk c holds logical
// chunk c ^ (row&7) -> a frag read (32 lanes at row-stride 128B) spreads
// across all 8 chunk columns (~2-way residual per quarter-wave, free).
// Stage: global_load_lds writes LINEAR (lane*16); the swizzle is applied by
// inverse-permuting the per-lane GLOBAL source chunk: (lane&7)^((lane>>3)&7).
// Read: addr = lane_const ^ (ks<<5) precomputed per ks (XOR is exact because
// chunk bits are disjoint: bit0 = lane>>5, bits1-2 = ks).
//
// Race structure (R4-proven): all of tile T+1 staged into buf^1 (never the
// live buffer) -> no intra-tile barriers; vmcnt(0) drains each wave's own
// 8 gloads, barrier makes all waves' stages visible, sched_barrier(0) stops
// next-tile ds_reads hoisting above the barrier.
// ---------------------------------------------------------------------------
#define GLOAD_LDS16(g, l)                                                     \
    __builtin_amdgcn_global_load_lds(                                         \
        (const __attribute__((address_space(1))) void*)(unsigned long long)(g),\
        (__attribute__((address_space(3))) void*)(unsigned int)(unsigned long long)(l), \
        16, 0, 0)

// 4 gloads: one 32-row x 64-elem subtile (wave-owned), rows in 8-row groups
#define STAGE4(p, d, kt, buf) do {                                            \
    const unsigned short* _s = (p) + (size_t)(kt) * 64;                       \
    GLOAD_LDS16(_s,                  smem + (buf) * 65536 + (d));             \
    GLOAD_LDS16(_s + 8 * K_DIM,      smem + (buf) * 65536 + (d) + 1024);      \
    GLOAD_LDS16(_s + 16 * K_DIM,     smem + (buf) * 65536 + (d) + 2048);      \
    GLOAD_LDS16(_s + 24 * K_DIM,     smem + (buf) * 65536 + (d) + 3072);      \
} while (0)

#define READA(DST, buf, fm) do {                                              \
    _Pragma("unroll") for (int ks = 0; ks < 4; ++ks)                          \
        DST[ks] = *(const bf16x8*)(smem + (buf) * 65536 + rdAoff +            \
                                   (fm) * 4096 + addr4[ks]);                  \
} while (0)

#define READB(buf) do {                                                       \
    _Pragma("unroll") for (int fn = 0; fn < 2; ++fn)                          \
        _Pragma("unroll") for (int ks = 0; ks < 4; ++ks)                      \
            bq[fn][ks] = *(const bf16x8*)(smem + (buf) * 65536 + rdBoff +     \
                                          (fn) * 4096 + addr4[ks]);           \
} while (0)

#define MMAQ(AR, fm) do {                                                     \
    _Pragma("unroll") for (int ks = 0; ks < 4; ++ks)                          \
        _Pragma("unroll") for (int fn = 0; fn < 2; ++fn)                      \
            acc[fm][fn] = __builtin_amdgcn_mfma_f32_32x32x16_bf16(            \
                AR[ks], bq[fn][ks], acc[fm][fn], 0, 0, 0);                    \
} while (0)

#define BARRIER __builtin_amdgcn_s_barrier()
#define WAIT_VM0 asm volatile("s_waitcnt vmcnt(0)" ::: "memory")
#define SCHED_FENCE __builtin_amdgcn_sched_barrier(0)
#define PRIO1 __builtin_amdgcn_s_setprio(1)
#define PRIO0 __builtin_amdgcn_s_setprio(0)

// One K-tile: stage T+1 into buf^1, compute over buf (A streamed per-fm).
#define KTILE(buf, tn) do {                                                   \
    STAGE4(pA, dA, (tn), (buf) ^ 1);                                          \
    STAGE4(pB, dB, (tn), (buf) ^ 1);                                          \
    READB((buf));                                                             \
    READA(a0, (buf), 0);                                                      \
    READA(a1, (buf), 1);                                                      \
    PRIO1; MMAQ(a0, 0); PRIO0;                                                \
    READA(a0, (buf), 2);                                                      \
    PRIO1; MMAQ(a1, 1); PRIO0;                                                \
    READA(a1, (buf), 3);                                                      \
    PRIO1; MMAQ(a0, 2); PRIO0;                                                \
    PRIO1; MMAQ(a1, 3); PRIO0;                                                \
    WAIT_VM0;                                                                 \
    BARRIER;                                                                  \
    SCHED_FENCE;                                                              \
} while (0)

__global__ __launch_bounds__(512, 2) void gemm_kernel(
        const unsigned short* __restrict__ X, const unsigned short* __restrict__ W,
        const float* __restrict__ bias, float* __restrict__ C) {
    __shared__ __align__(1024) unsigned char smem[131072];

    // XCD-aware chunked swizzle: 256 blocks, 8 XCDs, 32 contiguous wgs each
    const int pid = blockIdx.x;
    const int wg = (pid & 7) * 32 + (pid >> 3);
    const int bm = wg >> 4, bn = wg & 15;
    const int m0 = bm * 256, n0 = bn * 256;

    const int tid  = threadIdx.x;
    const int wave = tid >> 6;       // 0..7
    const int lane = tid & 63;
    const int wr   = wave >> 2;      // 0..1  (M half)
    const int wc   = wave & 3;       // 0..3  (N quarter)
    const int l31  = lane & 31;
    const int half = lane >> 5;

    // ---- staging: per-lane global source (inverse chunk swizzle) ----
    const int sgrow  = lane >> 3;                         // row within 8-row group
    const int schunk = (lane & 7) ^ (sgrow & 7);          // logical 16B chunk
    const unsigned short* pA = X + (size_t)(m0 + wave * 32 + sgrow) * K_DIM + schunk * 8;
    const unsigned short* pB = W + (size_t)(n0 + wave * 32 + sgrow) * K_DIM + schunk * 8;
    const int dA = wave * 4096 + lane * 16;               // linear LDS dest
    const int dB = 32768 + wave * 4096 + lane * 16;

    // ---- fragment read addressing (swizzled) ----
    // byte within subtile = row*128 + ((ks*2+half) ^ (row&7))*16, row = l31
    const int lane_const = (l31 << 7) | (((half ^ (lane & 7)) & 7) << 4);
    int addr4[4];
#pragma unroll
    for (int ks = 0; ks < 4; ++ks) addr4[ks] = lane_const ^ (ks << 5);

    const int rdAoff = (wr * 4) * 4096;           // + fm*4096
    const int rdBoff = 32768 + (wc * 2) * 4096;   // + fn*4096

    f32x16 acc[4][2] = {};
    bf16x8 a0[4], a1[4], bq[2][4];

    // ---- prologue: stage T0 into buf0, drain, sync ----
    STAGE4(pA, dA, 0, 0);
    STAGE4(pB, dB, 0, 0);
    WAIT_VM0;
    BARRIER;
    SCHED_FENCE;

#pragma unroll 1
    for (int it2 = 0; it2 < 32; ++it2) {
        const int ta = 2 * it2 + 1;          // staged during even tile
        const int tb = (2 * it2 + 2) & 63;   // staged during odd tile (wrap: dead)
        KTILE(0, ta);
        KTILE(1, tb);
    }

    // ---- epilogue: C/D col = lane&31, row = (reg&3)+8*(reg>>2)+4*half ----
    const int crow0 = m0 + wr * 128 + 4 * half;
    const int ccol0 = n0 + wc * 64 + l31;
    const float bv0 = bias[ccol0];
    const float bv1 = bias[ccol0 + 32];
#pragma unroll
    for (int fm = 0; fm < 4; ++fm) {
#pragma unroll
        for (int fn = 0; fn < 2; ++fn) {
            const int col = ccol0 + fn * 32;
            const float bv = fn ? bv1 : bv0;
#pragma unroll
            for (int reg = 0; reg < 16; ++reg) {
                const int row = crow0 + fm * 32 + (reg & 3) + 8 * (reg >> 2);
                C[(size_t)row * N_DIM + col] = acc[fm][fn][reg] + bv;
            }
        }
    }
}

// ---------------------------------------------------------------------------
extern "C" void kernel_launch(void* const* d_in, const int* in_sizes, int n_in,
                              void* d_out, int out_size, void* d_ws, size_t ws_size,
                              hipStream_t stream) {
    const float* x            = (const float*)d_in[0];
    const int*   nvfp4_idx    = (const int*)d_in[1];
    const float* nvfp4_scales = (const float*)d_in[2];
    const float* gscale       = (const float*)d_in[3];
    const float* w_fp8        = (const float*)d_in[4];
    const float* fp8_scale    = (const float*)d_in[5];
    const float* w_fp16       = (const float*)d_in[6];
    const float* bias         = (const float*)d_in[7];
    const int*   inv_perm     = (const int*)d_in[8];
    float* out = (float*)d_out;

    unsigned short* xb = (unsigned short*)d_ws;                 // 32 MiB
    unsigned short* wb = xb + (size_t)M_DIM * K_DIM;            // 32 MiB

    xconv_kernel<<<8192, 256, 0, stream>>>(x, xb);
    wbuild_kernel<<<4096, 256, 0, stream>>>(nvfp4_idx, nvfp4_scales, gscale,
                                            w_fp8, fp8_scale, w_fp16,
                                            inv_perm, wb);
    gemm_kernel<<<256, 512, 0, stream>>>(xb, wb, bias, out);
}